// Round 14
// baseline (1997.952 us; speedup 1.0000x reference)
//
#include <hip/hip_runtime.h>

// Problem: VQ-VAE codebook. z [32,256,32,32] f32, emb [8192,256] f32.
// Outputs concatenated in d_out (f32): z_q [8388608], idx [32768] (as float), loss [1].
//
// Scratch layout inside d_out's z_q region (consumed before k_out overwrites it):
//   [0 .. 2097152)        embT  (256 x 8192)   transposed codebook
//   [2097152 .. 2105344)  se    (8192)         ||e_k||^2
//   [2105344 .. 2138112)  sz    (32768)        ||z_n||^2
#define ZQ_OFF   0
#define EMBT_OFF 0
#define SE_OFF   2097152
#define SZ_OFF   2105344
#define IDX_OFF  8388608
#define LOSS_OFF 8421376

typedef float f32x2 __attribute__((ext_vector_type(2)));

// ---- fused prep: coalesced 64x64 LDS transpose emb -> embT[d][k]  +  se[k]  +  sz[n]
// blocks 0..511: transpose; 512..2559: se; 2560..2687: sz   (R13-proven)
__global__ void k_prep(const float* __restrict__ emb, float* __restrict__ embT,
                       float* __restrict__ se, const float* __restrict__ z,
                       float* __restrict__ sz) {
    const int blk = blockIdx.x;
    if (blk < 512) {
        __shared__ float tile[64][65];
        const int k0 = (blk & 127) * 64;          // 8192/64 = 128
        const int d0 = (blk >> 7) * 64;           // 256/64 = 4
        const int lane = threadIdx.x & 63;
        const int grp  = threadIdx.x >> 6;        // 0..3
        // read: 64 rows of emb (k), 64 cols (d) — coalesced along d
        #pragma unroll
        for (int i = 0; i < 16; ++i) {
            const int r = grp * 16 + i;
            tile[r][lane] = emb[(size_t)(k0 + r) * 256 + d0 + lane];
        }
        __syncthreads();
        // write: embT[d][k] — coalesced along k; tile read transposed (pad 65 -> conflict-free)
        #pragma unroll
        for (int i = 0; i < 16; ++i) {
            const int r = grp * 16 + i;
            embT[(size_t)(d0 + r) * 8192 + k0 + lane] = tile[lane][r];
        }
    } else if (blk < 2560) {
        int w    = ((blk - 512) * 256 + threadIdx.x) >> 6;    // code id
        int lane = threadIdx.x & 63;
        float4 v = *(const float4*)(emb + (size_t)w * 256 + lane * 4);
        float s = v.x * v.x + v.y * v.y + v.z * v.z + v.w * v.w;
        #pragma unroll
        for (int off = 1; off < 64; off <<= 1) s += __shfl_xor(s, off);
        if (lane == 0) se[w] = s;
    } else {
        // sz[n] = sum over c of z[b][c][hw]^2 (sequential chain over c ascending)
        int n  = (blk - 2560) * 256 + threadIdx.x;   // 128 blocks
        int b  = n >> 10, hw = n & 1023;
        const float* zp = z + (size_t)b * 262144 + hw;
        float acc = 0.f;
        #pragma unroll 8
        for (int c = 0; c < 256; ++c) { float v = zp[(size_t)c << 10]; acc += v * v; }
        sz[n] = acc;
    }
}

// packed dual FMA on a row-pair (z pair) x one code; EP holds 2 codes, op_sel picks which.
// even code: D.lo = z.lo*e.lo+acc.lo ; D.hi = z.hi*e.lo+acc.hi
#define PKFMA_EVEN(ACC, ZP, EP) \
    asm("v_pk_fma_f32 %0, %1, %2, %0 op_sel:[0,0,0] op_sel_hi:[1,0,1]" \
        : "+v"(ACC) : "v"(ZP), "v"(EP))
// odd code:  D.lo = z.lo*e.hi+acc.lo ; D.hi = z.hi*e.hi+acc.hi
#define PKFMA_ODD(ACC, ZP, EP) \
    asm("v_pk_fma_f32 %0, %1, %2, %0 op_sel:[0,1,0] op_sel_hi:[1,1,1]" \
        : "+v"(ACC) : "v"(ZP), "v"(EP))

// one d: 16 rows (8 z-pairs) x 8 codes (4 ef-pairs) = 64 pk ops = 128 FMAs.
// Each component is an IEEE fma -> bit-identical to the scalar fmaf chain.
#define FMA_BLOCK(Z, E0, E1) do {                                        \
    f32x2 ep_[4];                                                         \
    ep_[0] = ((const f32x2*)&(E0))[0]; ep_[1] = ((const f32x2*)&(E0))[1]; \
    ep_[2] = ((const f32x2*)&(E1))[0]; ep_[3] = ((const f32x2*)&(E1))[1]; \
    _Pragma("unroll")                                                     \
    for (int p_ = 0; p_ < 8; ++p_) {                                      \
        const f32x2 zp_ = ((const f32x2*)&(Z)[p_ >> 1])[p_ & 1];          \
        _Pragma("unroll")                                                 \
        for (int cp_ = 0; cp_ < 4; ++cp_) {                               \
            PKFMA_EVEN(accp[p_][cp_ * 2],     zp_, ep_[cp_]);             \
            PKFMA_ODD (accp[p_][cp_ * 2 + 1], zp_, ep_[cp_]);             \
        }                                                                 \
    }                                                                     \
} while (0)

#define LOADZ(DST, DD) do {                                              \
    _Pragma("unroll")                                                     \
    for (int i_ = 0; i_ < 4; ++i_)                                        \
        (DST)[i_] = *(const float4*)&ztT[DD][i_ * 4];                     \
} while (0)

#define LOADE(EA, EB, DD) do {                                           \
    const float* p_ = ep + (size_t)(DD) * 8192;                           \
    (EA) = *(const float4*)(p_);                                          \
    (EB) = *(const float4*)(p_ + 4);                                      \
} while (0)

// ---- main: exact-f32-replica distance + argmin.  (R12-proven, verbatim)
// 3-slot rotation pipeline, v_pk_fma_f32, 4-way code split, 16 rows/block, grid 2048.
// Per-tile argmin folded into LDS cwd/cwk (full lowest-k tie-break).
// d_nk = fl( fl(sz_n + se_k) - 2*m_nk ),  m = sequential fmaf chain over d=0..255 (BLAS order)
__global__ __launch_bounds__(256, 2) void k_main(
    const float* __restrict__ z, const float* __restrict__ embT,
    const float* __restrict__ se, const float* __restrict__ sz,
    float* __restrict__ idxf, float* __restrict__ lossslot) {
    __shared__ float ztT[256][16];        // [d][row]
    __shared__ float szs[16];
    __shared__ float cwd[4][16];          // [codegrp][row] best distance
    __shared__ int   cwk[4][16];          // matching code id
    const int tid = threadIdx.x;
    const int blk = blockIdx.x;           // grid = 2048
    const int n0  = blk * 16;
    const int b   = n0 >> 10, hw0 = n0 & 1023;

    // stage z tile transposed: ztT[c][n]; coalesced global reads over n
    {
        const int n  = tid & 15;
        const int cg = tid >> 4;                        // 0..15
        const float* zp = z + (size_t)b * 262144 + hw0 + n;
        #pragma unroll
        for (int cc = 0; cc < 256; cc += 16)
            ztT[cc + cg][n] = zp[(size_t)(cc + cg) << 10];
        if (tid < 16) szs[tid] = sz[n0 + tid];
        if (tid < 64) { (&cwd[0][0])[tid] = 3.4e38f; (&cwk[0][0])[tid] = 0; }
    }
    __syncthreads();

    const int w = tid >> 6;       // wave 0..3 -> code quarter w*512 within each tile
    const int j = tid & 63;       // lane -> 8 codes

    for (int tile = 0; tile < 4; ++tile) {
        const int c0 = tile * 2048 + w * 512 + j * 8;
        const float* ep = embT + c0;

        f32x2 accp[8][8];
        #pragma unroll
        for (int p = 0; p < 8; ++p)
            #pragma unroll
            for (int c = 0; c < 8; ++c) { accp[p][c].x = 0.f; accp[p][c].y = 0.f; }

        // prologue: z slot 0 <- d0; ef slots <- d0, d1, d2
        float4 z0[4], z1[4], z2[4];
        LOADZ(z0, 0);
        float4 e0a, e0b, e1a, e1b, e2a, e2b;
        LOADE(e0a, e0b, 0);
        LOADE(e1a, e1b, 1);
        LOADE(e2a, e2b, 2);

        // invariant entering body at `base`: z0 holds d=base, e_i holds d=base+i
        #pragma unroll 1
        for (int base = 0; base < 255; base += 3) {
            // pos 0: d = base
            LOADZ(z1, base + 1);
            FMA_BLOCK(z0, e0a, e0b);
            LOADE(e0a, e0b, base + 3);
            // pos 1: d = base+1
            LOADZ(z2, base + 2);
            FMA_BLOCK(z1, e1a, e1b);
            LOADE(e1a, e1b, base + 4);
            // pos 2: d = base+2
            LOADZ(z0, base + 3);
            FMA_BLOCK(z2, e2a, e2b);
            LOADE(e2a, e2b, base + 5);
        }
        // tail: d = 255. Overshoot ef reads (rows 256,257) land in the se/sz scratch
        // region (valid memory, never consumed); LOADZ(z0,255) from last body pos2.
        FMA_BLOCK(z0, e0a, e0b);

        // epilogue: dq = fl( fl(sz+se) - 2m ); codes ascending; strict < keeps first min
        const float4 seA = *(const float4*)(se + c0);
        const float4 seB = *(const float4*)(se + c0 + 4);
        #pragma unroll
        for (int rr = 0; rr < 16; ++rr) {
            const float szv = szs[rr];
            float bd = 3.4e38f; int bk = 0;
            #pragma unroll
            for (int c = 0; c < 8; ++c) {
                const float sek = (c < 4) ? ((const float*)&seA)[c]
                                          : ((const float*)&seB)[c - 4];
                const float m  = (rr & 1) ? accp[rr >> 1][c].y : accp[rr >> 1][c].x;
                float A  = szv + sek;
                float dq = A - 2.0f * m;
                if (dq < bd) { bd = dq; bk = c0 + c; }
            }
            // butterfly across 64 lanes; tie-break lowest k
            #pragma unroll
            for (int off = 1; off < 64; off <<= 1) {
                float od = __shfl_xor(bd, off);
                int   ok = __shfl_xor(bk, off);
                if (od < bd || (od == bd && ok < bk)) { bd = od; bk = ok; }
            }
            if (j == 0) {
                float pd = cwd[w][rr]; int pk = cwk[w][rr];
                if (bd < pd || (bd == pd && bk < pk)) { cwd[w][rr] = bd; cwk[w][rr] = bk; }
            }
        }
    }
    __syncthreads();
    // merge the 4 code-group partials per row with full (d,k) tie-break
    if (tid < 16) {
        float d = cwd[0][tid]; int k = cwk[0][tid];
        #pragma unroll
        for (int ww = 1; ww < 4; ++ww) {
            float od = cwd[ww][tid]; int ok = cwk[ww][tid];
            if (od < d || (od == d && ok < k)) { d = od; k = ok; }
        }
        idxf[n0 + tid] = (float)k;
    }
    if (blk == 0 && tid == 0) *lossslot = 0.f;   // init loss accumulator (runs before k_out)
}

// ---- z_q (STE-exact) + loss partial sums
__global__ void k_out(const float* __restrict__ z, const float* __restrict__ emb,
                      const float* __restrict__ idxf, float* __restrict__ zq,
                      float* __restrict__ lossslot) {
    int u   = blockIdx.x * 256 + threadIdx.x;   // grid = 8192 blocks (2M threads)
    int cc4 = u >> 15;                          // 0..63 (uniform per block)
    int n   = u & 32767;
    int b   = n >> 10, hw = n & 1023;
    int k   = (int)idxf[n];
    const float4 q4 = *(const float4*)(emb + (size_t)k * 256 + cc4 * 4);
    float ls = 0.f;
    #pragma unroll
    for (int c = 0; c < 4; ++c) {
        size_t zi = (size_t)b * 262144 + (size_t)(cc4 * 4 + c) * 1024 + hw;
        float zv   = z[zi];
        float qv   = ((const float*)&q4)[c];
        float diff = qv - zv;        // fl(q - z)
        zq[zi]     = zv + diff;      // fl(z + fl(q - z))  == reference STE output
        ls += diff * diff;
    }
    #pragma unroll
    for (int off = 1; off < 64; off <<= 1) ls += __shfl_xor(ls, off);
    if ((threadIdx.x & 63) == 0) atomicAdd(lossslot, ls);
}

__global__ void k_fin(float* __restrict__ lossslot) {
    float S = *lossslot;
    float m = S / 8388608.0f;        // /2^23 exact scaling
    *lossslot = m + 0.25f * m;       // fl(m1 + fl(beta*m2)), m1==m2
}

extern "C" void kernel_launch(void* const* d_in, const int* in_sizes, int n_in,
                              void* d_out, int out_size, void* d_ws, size_t ws_size,
                              hipStream_t stream) {
    const float* z   = (const float*)d_in[0];
    const float* emb = (const float*)d_in[1];
    float* out  = (float*)d_out;
    float* embT = out + EMBT_OFF;
    float* se   = out + SE_OFF;
    float* sz   = out + SZ_OFF;
    float* idxf = out + IDX_OFF;
    float* loss = out + LOSS_OFF;

    k_prep<<<2688, 256, 0, stream>>>(emb, embT, se, z, sz);
    k_main<<<2048, 256, 0, stream>>>(z, embT, se, sz, idxf, loss);
    k_out<<<8192, 256, 0, stream>>>(z, emb, idxf, out + ZQ_OFF, loss);
    k_fin<<<1, 1, 0, stream>>>(loss);
}

// Round 15
// 1507.235 us; speedup vs baseline: 1.3256x; 1.3256x over previous
//
#include <hip/hip_runtime.h>

// Problem: VQ-VAE codebook. z [32,256,32,32] f32, emb [8192,256] f32.
// Outputs concatenated in d_out (f32): z_q [8388608], idx [32768] (as float), loss [1].
//
// Preferred layout: scratch in d_ws (embT 2097152 f, se 8192 f, sz 32768 f = 8.6 MB)
// -> z_q region is hazard-free and k_main writes z_q + loss in its epilogue (no k_out).
// Fallback (ws too small): scratch inside the z_q region (R14 layout) + separate k_out.
#define ZQ_OFF   0
#define SE_OFF   2097152
#define SZ_OFF   2105344
#define IDX_OFF  8388608
#define LOSS_OFF 8421376
#define WS_FLOATS 2138112          // embT + se + sz

typedef float f32x2 __attribute__((ext_vector_type(2)));

// ---- fused prep: coalesced 64x64 LDS transpose emb -> embT[d][k]  +  se[k]  +  sz[n]
// blocks 0..511: transpose; 512..2559: se; 2560..2687: sz   (R13-proven)
__global__ void k_prep(const float* __restrict__ emb, float* __restrict__ embT,
                       float* __restrict__ se, const float* __restrict__ z,
                       float* __restrict__ sz, float* __restrict__ lossslot) {
    const int blk = blockIdx.x;
    if (blk == 0 && threadIdx.x == 0) *lossslot = 0.f;   // ordered before all atomics
    if (blk < 512) {
        __shared__ float tile[64][65];
        const int k0 = (blk & 127) * 64;          // 8192/64 = 128
        const int d0 = (blk >> 7) * 64;           // 256/64 = 4
        const int lane = threadIdx.x & 63;
        const int grp  = threadIdx.x >> 6;        // 0..3
        #pragma unroll
        for (int i = 0; i < 16; ++i) {
            const int r = grp * 16 + i;
            tile[r][lane] = emb[(size_t)(k0 + r) * 256 + d0 + lane];
        }
        __syncthreads();
        #pragma unroll
        for (int i = 0; i < 16; ++i) {
            const int r = grp * 16 + i;
            embT[(size_t)(d0 + r) * 8192 + k0 + lane] = tile[lane][r];
        }
    } else if (blk < 2560) {
        int w    = ((blk - 512) * 256 + threadIdx.x) >> 6;    // code id
        int lane = threadIdx.x & 63;
        float4 v = *(const float4*)(emb + (size_t)w * 256 + lane * 4);
        float s = v.x * v.x + v.y * v.y + v.z * v.z + v.w * v.w;
        #pragma unroll
        for (int off = 1; off < 64; off <<= 1) s += __shfl_xor(s, off);
        if (lane == 0) se[w] = s;
    } else {
        // sz[n] = sum over c of z[b][c][hw]^2 (sequential chain over c ascending)
        int n  = (blk - 2560) * 256 + threadIdx.x;   // 128 blocks
        int b  = n >> 10, hw = n & 1023;
        const float* zp = z + (size_t)b * 262144 + hw;
        float acc = 0.f;
        #pragma unroll 8
        for (int c = 0; c < 256; ++c) { float v = zp[(size_t)c << 10]; acc += v * v; }
        sz[n] = acc;
    }
}

// packed dual FMA on a row-pair (z pair) x one code; EP holds 2 codes, op_sel picks which.
#define PKFMA_EVEN(ACC, ZP, EP) \
    asm("v_pk_fma_f32 %0, %1, %2, %0 op_sel:[0,0,0] op_sel_hi:[1,0,1]" \
        : "+v"(ACC) : "v"(ZP), "v"(EP))
#define PKFMA_ODD(ACC, ZP, EP) \
    asm("v_pk_fma_f32 %0, %1, %2, %0 op_sel:[0,1,0] op_sel_hi:[1,1,1]" \
        : "+v"(ACC) : "v"(ZP), "v"(EP))

// one d: 16 rows (8 z-pairs) x 8 codes (4 ef-pairs) = 64 pk ops = 128 FMAs.
// Each component is an IEEE fma -> bit-identical to the scalar fmaf chain.
#define FMA_BLOCK(Z, E0, E1) do {                                        \
    f32x2 ep_[4];                                                         \
    ep_[0] = ((const f32x2*)&(E0))[0]; ep_[1] = ((const f32x2*)&(E0))[1]; \
    ep_[2] = ((const f32x2*)&(E1))[0]; ep_[3] = ((const f32x2*)&(E1))[1]; \
    _Pragma("unroll")                                                     \
    for (int p_ = 0; p_ < 8; ++p_) {                                      \
        const f32x2 zp_ = ((const f32x2*)&(Z)[p_ >> 1])[p_ & 1];          \
        _Pragma("unroll")                                                 \
        for (int cp_ = 0; cp_ < 4; ++cp_) {                               \
            PKFMA_EVEN(accp[p_][cp_ * 2],     zp_, ep_[cp_]);             \
            PKFMA_ODD (accp[p_][cp_ * 2 + 1], zp_, ep_[cp_]);             \
        }                                                                 \
    }                                                                     \
} while (0)

#define LOADZ(DST, DD) do {                                              \
    _Pragma("unroll")                                                     \
    for (int i_ = 0; i_ < 4; ++i_)                                        \
        (DST)[i_] = *(const float4*)&ztT[DD][i_ * 4];                     \
} while (0)

#define LOADE(EA, EB, DD) do {                                           \
    const float* p_ = ep + (size_t)(DD) * 8192;                           \
    (EA) = *(const float4*)(p_);                                          \
    (EB) = *(const float4*)(p_ + 4);                                      \
} while (0)

// ---- main: exact-f32-replica distance + argmin (R12-proven core) + optional fused
// z_q/loss epilogue (fused=1 only when scratch lives in d_ws -> no write hazard).
// d_nk = fl( fl(sz_n + se_k) - 2*m_nk ),  m = sequential fmaf chain over d=0..255 (BLAS order)
__global__ __launch_bounds__(256, 2) void k_main(
    const float* __restrict__ z, const float* __restrict__ embT,
    const float* __restrict__ se, const float* __restrict__ sz,
    float* __restrict__ idxf, float* __restrict__ lossslot,
    const float* __restrict__ embf, float* __restrict__ zq, const int fused) {
    __shared__ float ztT[256][16];        // [d][row]
    __shared__ float szs[16];
    __shared__ float cwd[4][16];          // [codegrp][row] best distance
    __shared__ int   cwk[4][16];          // matching code id
    __shared__ int   kfin[16];
    const int tid = threadIdx.x;
    const int blk = blockIdx.x;           // grid = 2048
    const int n0  = blk * 16;
    const int b   = n0 >> 10, hw0 = n0 & 1023;

    // stage z tile transposed: ztT[c][n]; coalesced global reads over n
    {
        const int n  = tid & 15;
        const int cg = tid >> 4;                        // 0..15
        const float* zp = z + (size_t)b * 262144 + hw0 + n;
        #pragma unroll
        for (int cc = 0; cc < 256; cc += 16)
            ztT[cc + cg][n] = zp[(size_t)(cc + cg) << 10];
        if (tid < 16) szs[tid] = sz[n0 + tid];
        if (tid < 64) { (&cwd[0][0])[tid] = 3.4e38f; (&cwk[0][0])[tid] = 0; }
    }
    __syncthreads();

    const int w = tid >> 6;       // wave 0..3 -> code quarter w*512 within each tile
    const int j = tid & 63;       // lane -> 8 codes

    for (int tile = 0; tile < 4; ++tile) {
        const int c0 = tile * 2048 + w * 512 + j * 8;
        const float* ep = embT + c0;

        f32x2 accp[8][8];
        #pragma unroll
        for (int p = 0; p < 8; ++p)
            #pragma unroll
            for (int c = 0; c < 8; ++c) { accp[p][c].x = 0.f; accp[p][c].y = 0.f; }

        // prologue: z slot 0 <- d0; ef slots <- d0, d1, d2
        float4 z0[4], z1[4], z2[4];
        LOADZ(z0, 0);
        float4 e0a, e0b, e1a, e1b, e2a, e2b;
        LOADE(e0a, e0b, 0);
        LOADE(e1a, e1b, 1);
        LOADE(e2a, e2b, 2);

        // invariant entering body at `base`: z0 holds d=base, e_i holds d=base+i
        #pragma unroll 1
        for (int base = 0; base < 255; base += 3) {
            LOADZ(z1, base + 1);
            FMA_BLOCK(z0, e0a, e0b);
            LOADE(e0a, e0b, base + 3);
            LOADZ(z2, base + 2);
            FMA_BLOCK(z1, e1a, e1b);
            LOADE(e1a, e1b, base + 4);
            LOADZ(z0, base + 3);
            FMA_BLOCK(z2, e2a, e2b);
            LOADE(e2a, e2b, base + 5);
        }
        // tail: d = 255. Overshoot ef reads (rows 256,257) land in the se/sz region
        // directly after embT (valid memory, never consumed).
        FMA_BLOCK(z0, e0a, e0b);

        // epilogue: dq = fl( fl(sz+se) - 2m ); codes ascending; strict < keeps first min
        const float4 seA = *(const float4*)(se + c0);
        const float4 seB = *(const float4*)(se + c0 + 4);
        #pragma unroll
        for (int rr = 0; rr < 16; ++rr) {
            const float szv = szs[rr];
            float bd = 3.4e38f; int bk = 0;
            #pragma unroll
            for (int c = 0; c < 8; ++c) {
                const float sek = (c < 4) ? ((const float*)&seA)[c]
                                          : ((const float*)&seB)[c - 4];
                const float m  = (rr & 1) ? accp[rr >> 1][c].y : accp[rr >> 1][c].x;
                float A  = szv + sek;
                float dq = A - 2.0f * m;
                if (dq < bd) { bd = dq; bk = c0 + c; }
            }
            #pragma unroll
            for (int off = 1; off < 64; off <<= 1) {     // tie-break lowest k
                float od = __shfl_xor(bd, off);
                int   ok = __shfl_xor(bk, off);
                if (od < bd || (od == bd && ok < bk)) { bd = od; bk = ok; }
            }
            if (j == 0) {
                float pd = cwd[w][rr]; int pk = cwk[w][rr];
                if (bd < pd || (bd == pd && bk < pk)) { cwd[w][rr] = bd; cwk[w][rr] = bk; }
            }
        }
    }
    __syncthreads();
    // merge the 4 code-group partials per row with full (d,k) tie-break
    if (tid < 16) {
        float d = cwd[0][tid]; int k = cwk[0][tid];
        #pragma unroll
        for (int ww = 1; ww < 4; ++ww) {
            float od = cwd[ww][tid]; int ok = cwk[ww][tid];
            if (od < d || (od == d && ok < k)) { d = od; k = ok; }
        }
        idxf[n0 + tid] = (float)k;
        kfin[tid] = k;
    }
    if (!fused) return;
    __syncthreads();

    // fused z_q + loss epilogue: thread t owns channel c = t for all 16 rows.
    // zq[b][c][hw0+r] = fl(z + fl(e - z)) — z re-read coalesced from global (same bits
    // as ztT), e = emb[k_r][c] coalesced across lanes per row.
    {
        const int c = tid;
        const float* zsrc = z + (size_t)b * 262144 + (size_t)c * 1024 + hw0;
        float4 zv4[4];
        #pragma unroll
        for (int q = 0; q < 4; ++q) zv4[q] = *(const float4*)(zsrc + q * 4);
        float outv[16];
        float ls = 0.f;
        #pragma unroll
        for (int r = 0; r < 16; ++r) {
            const float e    = embf[(size_t)kfin[r] * 256 + c];
            const float zv   = ((const float*)&zv4[r >> 2])[r & 3];
            const float diff = e - zv;         // fl(e - z)
            outv[r] = zv + diff;               // fl(z + fl(e - z))
            ls += diff * diff;
        }
        float* dst = zq + (size_t)b * 262144 + (size_t)c * 1024 + hw0;
        #pragma unroll
        for (int q = 0; q < 4; ++q)
            *(float4*)(dst + q * 4) = *(const float4*)(&outv[q * 4]);
        #pragma unroll
        for (int off = 1; off < 64; off <<= 1) ls += __shfl_xor(ls, off);
        if ((tid & 63) == 0) atomicAdd(lossslot, ls);
    }
}

// ---- fallback z_q (STE-exact) + loss partial sums (used only when ws is too small)
__global__ void k_out(const float* __restrict__ z, const float* __restrict__ emb,
                      const float* __restrict__ idxf, float* __restrict__ zq,
                      float* __restrict__ lossslot) {
    int u   = blockIdx.x * 256 + threadIdx.x;   // grid = 8192 blocks (2M threads)
    int cc4 = u >> 15;                          // 0..63 (uniform per block)
    int n   = u & 32767;
    int b   = n >> 10, hw = n & 1023;
    int k   = (int)idxf[n];
    const float4 q4 = *(const float4*)(emb + (size_t)k * 256 + cc4 * 4);
    float ls = 0.f;
    #pragma unroll
    for (int c = 0; c < 4; ++c) {
        size_t zi = (size_t)b * 262144 + (size_t)(cc4 * 4 + c) * 1024 + hw;
        float zv   = z[zi];
        float qv   = ((const float*)&q4)[c];
        float diff = qv - zv;
        zq[zi]     = zv + diff;
        ls += diff * diff;
    }
    #pragma unroll
    for (int off = 1; off < 64; off <<= 1) ls += __shfl_xor(ls, off);
    if ((threadIdx.x & 63) == 0) atomicAdd(lossslot, ls);
}

__global__ void k_fin(float* __restrict__ lossslot) {
    float S = *lossslot;
    float m = S / 8388608.0f;        // /2^23 exact scaling
    *lossslot = m + 0.25f * m;       // fl(m1 + fl(beta*m2)), m1==m2
}

extern "C" void kernel_launch(void* const* d_in, const int* in_sizes, int n_in,
                              void* d_out, int out_size, void* d_ws, size_t ws_size,
                              hipStream_t stream) {
    const float* z   = (const float*)d_in[0];
    const float* emb = (const float*)d_in[1];
    float* out  = (float*)d_out;
    float* idxf = out + IDX_OFF;
    float* loss = out + LOSS_OFF;

    const bool use_ws = (d_ws != nullptr) && (ws_size >= (size_t)WS_FLOATS * 4);
    float* embT; float* se; float* sz; int fused;
    if (use_ws) {
        float* ws = (float*)d_ws;
        embT = ws; se = ws + 2097152; sz = ws + 2105344; fused = 1;
    } else {
        embT = out; se = out + SE_OFF; sz = out + SZ_OFF; fused = 0;
    }

    k_prep<<<2688, 256, 0, stream>>>(emb, embT, se, z, sz, loss);
    k_main<<<2048, 256, 0, stream>>>(z, embT, se, sz, idxf, loss,
                                     emb, out + ZQ_OFF, fused);
    if (!fused)
        k_out<<<8192, 256, 0, stream>>>(z, emb, idxf, out + ZQ_OFF, loss);
    k_fin<<<1, 1, 0, stream>>>(loss);
}